// Round 9
// baseline (612.692 us; speedup 1.0000x reference)
//
#include <hip/hip_runtime.h>
#include <math.h>

#define B_    32
#define C_    64
#define T_    512
#define NROWS (B_ * C_)
#define CMAX_ 16
#define FEPS  1.1920929e-07f
#define PI_F  3.14159265358979323846f

// gelu via sigmoid form of the tanh approximation (max abs err ~3e-4):
// gelu(x) = x * sigmoid(1.5957692*(x + 0.044715 x^3)) ; exp2 constant = 2*0.7978845608*log2(e)
__device__ __forceinline__ float gelu_fast(float x) {
    float y = fmaf(0.044715f * x * x, x, x);
    float e = __builtin_exp2f(-2.3022808f * y);
    return x * __builtin_amdgcn_rcpf(1.0f + e);
}

// ---------------- mono kernel: rFFT + top-3 + fold/conv/pools/seq ----------
// One row per block, 128 threads (2 waves).
__global__ __launch_bounds__(128, 4) void mono_kernel(
    const float* __restrict__ feat,
    const float* __restrict__ w0, const float* __restrict__ b0,
    const float* __restrict__ w1, const float* __restrict__ b1,
    const float* __restrict__ w2, const float* __restrict__ b2,
    const float* __restrict__ wpj, const float* __restrict__ bpj,
    const float* __restrict__ wr, const float* __restrict__ br,
    float* __restrict__ avg_out, float* __restrict__ max_out,
    float* __restrict__ seq_out)
{
    __shared__ float rowp[1040];         // rowp[2+i] = row[i]; tail zero-filled
    __shared__ __align__(16) float2 FA[256];
    __shared__ __align__(16) float2 FB[256];
    __shared__ float WeffS[80];
    __shared__ float wtopS[6];
    __shared__ int   itopS[6];
    __shared__ int   ipS[9];             // P[3], cyc[3], base[3]
    __shared__ float bwS[3];

    const int tid = threadIdx.x;         // 0..127
    const int r = blockIdx.x;

    // ---- stage row into padded LDS; zero tail so no clamps needed ----
    {
        float4 v = reinterpret_cast<const float4*>(feat + (size_t)r * T_)[tid];
        int bi = 2 + tid * 4;
        rowp[bi + 0] = v.x; rowp[bi + 1] = v.y;
        rowp[bi + 2] = v.z; rowp[bi + 3] = v.w;
    }
    for (int i = 514 + tid; i < 1040; i += 128) rowp[i] = 0.f;
    if (tid == 0) { rowp[0] = 0.f; rowp[1] = 0.f; }
    if (tid < 80) {
        int i = tid;
        if (i < 75) {
            int k = i / 25, ij = i % 25, ii = ij / 5, jj = ij % 5;
            float w = wpj[2] * w2[k * 25 + ii * 5 + jj];
            if (ii >= 1 && ii <= 3 && jj >= 1 && jj <= 3)
                w += wpj[1] * w1[k * 9 + (ii - 1) * 3 + (jj - 1)];
            if (ii == 2 && jj == 2) w += wpj[0] * w0[k];
            WeffS[i] = w;
        } else if (i == 75) {
            WeffS[75] = wpj[0] * b0[0] + wpj[1] * b1[0] + wpj[2] * b2[0] + bpj[0];
        } else if (i <= 78) {
            WeffS[i] = wr[i - 76];
        } else {
            WeffS[79] = br[0];
        }
    }
    __syncthreads();

    // ---- pack reals into 256 complex: z[n] = x[2n] + i x[2n+1] ----
    FA[tid]       = make_float2(rowp[2 + 2 * tid],         rowp[2 + 2 * tid + 1]);
    FA[tid + 128] = make_float2(rowp[2 + 2 * (tid + 128)], rowp[2 + 2 * (tid + 128) + 1]);
    __syncthreads();

    // ---- 8-stage Stockham radix-2 FFT (256-pt complex), ping-pong FA/FB ----
    {
        float2* src = FA;
        float2* dst = FB;
        #pragma unroll
        for (int s = 1; s <= 8; ++s) {
            const int l = 1 << (s - 1);
            const int p = tid & (l - 1);
            const int i0 = 2 * tid - p;
            // twiddle e^{-i*pi*p/l}: revolutions = p/(2l) (exact)
            const float rev = (float)p * (0.5f / (float)l);
            const float cw =  __builtin_amdgcn_cosf(rev);
            const float sw = -__builtin_amdgcn_sinf(rev);
            float2 a = src[tid];
            float2 b = src[tid + 128];
            float tr = cw * b.x - sw * b.y;
            float ti = cw * b.y + sw * b.x;
            dst[i0]     = make_float2(a.x + tr, a.y + ti);
            dst[i0 + l] = make_float2(a.x - tr, a.y - ti);
            __syncthreads();
            float2* tmp = src; src = dst; dst = tmp;
        }
    }

    // ---- rfft unpack: thread j -> bins k = j+1 and k = j+129; amp = |F[k]| ----
    float v[2]; int id[2];
    #pragma unroll
    for (int q = 0; q < 2; ++q) {
        const int k = 1 + tid + 128 * q;
        float2 A  = FA[k & 255];
        float2 Bv = FA[(256 - k) & 255];
        float Er = 0.5f * (A.x + Bv.x);
        float Ei = 0.5f * (A.y - Bv.y);
        float Or = 0.5f * (A.y + Bv.y);
        float Oi = 0.5f * (Bv.x - A.x);
        const float rev = (float)k * (1.0f / 512.0f);   // k*pi/256 in revolutions
        float sth = __builtin_amdgcn_sinf(rev);
        float cth = __builtin_amdgcn_cosf(rev);
        float Fr = Er + cth * Or + sth * Oi;
        float Fi = Ei + cth * Oi - sth * Or;
        v[q] = sqrtf(Fr * Fr + Fi * Fi);
        id[q] = k;
    }

    // ---- wave-local top-3 then cross-wave merge ----
    {
        const int wv = tid >> 6;
        float vals[3]; int idxs[3];
        #pragma unroll
        for (int kk = 0; kk < 3; ++kk) {
            float bv = v[0]; int bi = id[0];
            if (v[1] > bv || (v[1] == bv && id[1] < bi)) { bv = v[1]; bi = id[1]; }
            #pragma unroll
            for (int off = 32; off >= 1; off >>= 1) {
                float ov = __shfl_xor(bv, off, 64);
                int   oi = __shfl_xor(bi, off, 64);
                if (ov > bv || (ov == bv && oi < bi)) { bv = ov; bi = oi; }
            }
            vals[kk] = bv; idxs[kk] = bi;
            #pragma unroll
            for (int q = 0; q < 2; ++q)
                if (id[q] == bi) v[q] = -1e30f;
        }
        if ((tid & 63) == 0) {
            #pragma unroll
            for (int kk = 0; kk < 3; ++kk) {
                wtopS[wv * 3 + kk] = vals[kk];
                itopS[wv * 3 + kk] = idxs[kk];
            }
        }
    }
    __syncthreads();
    if (tid == 0) {
        float vv[6]; int ii[6];
        #pragma unroll
        for (int q = 0; q < 6; ++q) { vv[q] = wtopS[q]; ii[q] = itopS[q]; }
        float vals[3]; int idxs[3];
        #pragma unroll
        for (int kk = 0; kk < 3; ++kk) {
            float bv = vv[0]; int bi = ii[0];
            #pragma unroll
            for (int q = 1; q < 6; ++q)
                if (vv[q] > bv || (vv[q] == bv && ii[q] < bi)) { bv = vv[q]; bi = ii[q]; }
            vals[kk] = bv; idxs[kk] = bi;
            #pragma unroll
            for (int q = 0; q < 6; ++q)
                if (ii[q] == bi) vv[q] = -1e30f;
        }
        float m = fmaxf(vals[0], fmaxf(vals[1], vals[2]));
        float e0 = expf(vals[0] - m), e1 = expf(vals[1] - m), e2 = expf(vals[2] - m);
        float inv = 1.0f / (e0 + e1 + e2);
        bwS[0] = e0 * inv; bwS[1] = e1 * inv; bwS[2] = e2 * inv;
        #pragma unroll
        for (int kk = 0; kk < 3; ++kk) {
            int fi = idxs[kk];
            int P = T_ / fi;
            P = P < 32 ? 32 : (P > 512 ? 512 : P);
            int cyc = T_ / P;
            ipS[kk] = P; ipS[3 + kk] = cyc; ipS[6 + kk] = T_ - cyc * P;
        }
    }
    __syncthreads();

    // ---- fold + conv + pools + merged seq ----
    const int P0  = __builtin_amdgcn_readfirstlane(ipS[0]);
    const int P1  = __builtin_amdgcn_readfirstlane(ipS[1]);
    const int P2  = __builtin_amdgcn_readfirstlane(ipS[2]);
    const int cy0 = __builtin_amdgcn_readfirstlane(ipS[3]);
    const int cy1 = __builtin_amdgcn_readfirstlane(ipS[4]);
    const int cy2 = __builtin_amdgcn_readfirstlane(ipS[5]);
    const int bs0 = __builtin_amdgcn_readfirstlane(ipS[6]);
    const int bs1 = __builtin_amdgcn_readfirstlane(ipS[7]);
    const int bs2 = __builtin_amdgcn_readfirstlane(ipS[8]);
    const float bw0 = bwS[0], bw1 = bwS[1], bw2 = bwS[2];
    const float beff = WeffS[75], wr0 = WeffS[76], wr1 = WeffS[77],
                wr2 = WeffS[78], bres = WeffS[79];

    // hoist all 75 conv weights into registers (static indexing everywhere)
    float Wreg[3][5][5];
    #pragma unroll
    for (int k = 0; k < 3; ++k)
        #pragma unroll
        for (int i = 0; i < 5; ++i)
            #pragma unroll
            for (int j = 0; j < 5; ++j)
                Wreg[k][i][j] = WeffS[k * 25 + i * 5 + j];

    int maxP = P0 > P1 ? P0 : P1; maxP = maxP > P2 ? maxP : P2;
    const int PkA[3]  = {P0, P1, P2};
    const int cykA[3] = {cy0, cy1, cy2};
    const int bskA[3] = {bs0, bs1, bs2};
    const int woff = tid & 64;          // wave base within chunk

    #pragma unroll 1
    for (int pc = 0; pc < T_; pc += 128) {
        const int p = pc + tid;
        const int wb = __builtin_amdgcn_readfirstlane(pc + woff);
        if (wb >= maxP) {
            avg_out[r * T_ + p] = 0.f;
            max_out[r * T_ + p] = 0.f;
            seq_out[r * T_ + p] = 0.f;
            continue;
        }
        int c0 = (P0 > wb) ? cy0 : 0;
        int c1 = (P1 > wb) ? cy1 : 0;
        int c2 = (P2 > wb) ? cy2 : 0;
        int cymax = c0 > c1 ? c0 : c1; cymax = cymax > c2 ? cymax : c2;
        cymax = __builtin_amdgcn_readfirstlane(cymax);

        float zacc[CMAX_];
        #pragma unroll
        for (int i = 0; i < CMAX_; ++i) zacc[i] = beff;

        // ---- conv: software-pipelined taps, no clamps (big rowp) ----
        #pragma unroll
        for (int k = 0; k < 3; ++k) {
            const int P = PkA[k];
            if (wb >= P) continue;          // wave-uniform skip
            const int cy = cykA[k];
            const int bs = bskA[k];
            bool mdw[5];
            #pragma unroll
            for (int dw = -2; dw <= 2; ++dw)
                mdw[dw + 2] = ((unsigned)(p + dw) < (unsigned)P);
            const int base = bs + p;        // tap addr = base + hh*P + dw (dw offset by +0..4 from base-2+2)
            float cur[5], nxt[5];
            #pragma unroll
            for (int dw = 0; dw < 5; ++dw) { cur[dw] = rowp[base + dw]; nxt[dw] = 0.f; }
            #pragma unroll
            for (int hh = 0; hh < CMAX_; ++hh) {
                if (hh < cy) {              // lane-uniform guard
                    if (hh + 1 < cy) {      // prefetch next window
                        const int a = base + (hh + 1) * P;
                        #pragma unroll
                        for (int dw = 0; dw < 5; ++dw) nxt[dw] = rowp[a + dw];
                    }
                    float w[5];
                    #pragma unroll
                    for (int dw = 0; dw < 5; ++dw) w[dw] = mdw[dw] ? cur[dw] : 0.f;
                    #pragma unroll
                    for (int dh = -2; dh <= 2; ++dh) {
                        const int cc = hh - dh;     // compile-time
                        if (cc >= 0 && cc < CMAX_) {
                            #pragma unroll
                            for (int dw = 0; dw < 5; ++dw)
                                zacc[cc] = fmaf(Wreg[k][dh + 2][dw], w[dw], zacc[cc]);
                        }
                    }
                    #pragma unroll
                    for (int dw = 0; dw < 5; ++dw) cur[dw] = nxt[dw];
                }
            }
        }

        // ---- pools + merged branch sums ----
        float avg_num = 0.f, den = 0.f, mx = -3.402823466e38f;
        float s0 = 0.f, s1 = 0.f, s2 = 0.f;
        int anyv = 0;
        const int pl0 = (p < P0), pl1 = (p < P1), pl2 = (p < P2);
        #pragma unroll
        for (int cc = 0; cc < CMAX_; ++cc) {
            if (cc < cymax) {               // uniform guard
                int m0 = (cc < cy0) & pl0;
                int m1 = (cc < cy1) & pl1;
                int m2 = (cc < cy2) & pl2;
                float x0v = m0 ? rowp[2 + bs0 + cc * P0 + p] : 0.f;
                float x1v = m1 ? rowp[2 + bs1 + cc * P1 + p] : 0.f;
                float x2v = m2 ? rowp[2 + bs2 + cc * P2 + p] : 0.f;
                float res = fmaf(wr0, x0v, fmaf(wr1, x1v, fmaf(wr2, x2v, bres)));
                float z = gelu_fast(zacc[cc]) + res;
                s0 += x0v; s1 += x1v; s2 += x2v;
                int mm = m0 | m1 | m2;
                float cm = mm ? 1.f : 0.f;
                avg_num += z * cm;
                den += cm;
                mx = mm ? fmaxf(mx, z) : mx;
                anyv |= mm;
            }
        }
        float avg = avg_num / (den + FEPS);
        float mpool = anyv ? mx : 0.f;

        float seq = 0.f;
        seq = fmaf(bw0, pl0 ? s0 / ((float)cy0 + FEPS) : 0.f, seq);
        seq = fmaf(bw1, pl1 ? s1 / ((float)cy1 + FEPS) : 0.f, seq);
        seq = fmaf(bw2, pl2 ? s2 / ((float)cy2 + FEPS) : 0.f, seq);

        avg_out[r * T_ + p] = avg;
        max_out[r * T_ + p] = mpool;
        seq_out[r * T_ + p] = seq;
    }
}

// ---------- fuse GEMM + gelu ----------
// grid (16 t-tiles, 32 b), 256 threads, 64o x 32t tile, 2o x 4t micro.
__global__ __launch_bounds__(256) void fuse_kernel(
    const float* __restrict__ avgb, const float* __restrict__ maxb,
    const float* __restrict__ seqb,
    const float* __restrict__ wf, const float* __restrict__ bfu,
    float* __restrict__ out)
{
    __shared__ float wT[64][70];    // wT[c][o]
    __shared__ float Bt[64][40];    // Bt[c][t]
    const int tid = threadIdx.x;
    const int b = blockIdx.y;
    const int tt0 = blockIdx.x * 32;
    const int og = tid >> 3;        // 0..31
    const int tg = tid & 7;         // 0..7
    const int o0 = og * 2;
    const int t0 = tg * 4;

    float acc[2][4];
    #pragma unroll
    for (int i = 0; i < 2; ++i)
        #pragma unroll
        for (int j = 0; j < 4; ++j) acc[i][j] = 0.f;

    const float* srcs[3] = {avgb, maxb, seqb};
    for (int g = 0; g < 3; ++g) {
        const float* __restrict__ src = srcs[g];
        #pragma unroll
        for (int it = 0; it < 2; ++it) {
            int idx = tid + it * 256;          // 0..511
            int c = idx >> 3, t4 = idx & 7;
            float4 vv = reinterpret_cast<const float4*>(
                            &src[(b * 64 + c) * 512 + tt0])[t4];
            *reinterpret_cast<float4*>(&Bt[c][t4 * 4]) = vv;
        }
        #pragma unroll
        for (int it = 0; it < 16; ++it) {
            int i = tid + it * 256;            // 0..4095
            int c = i & 63, o = i >> 6;
            wT[c][o] = wf[o * 192 + g * 64 + c];
        }
        __syncthreads();
        for (int c = 0; c < 64; ++c) {
            float2 wv = *reinterpret_cast<const float2*>(&wT[c][o0]);
            float4 bv = *reinterpret_cast<const float4*>(&Bt[c][t0]);
            const float wa[2] = {wv.x, wv.y};
            const float ba[4] = {bv.x, bv.y, bv.z, bv.w};
            #pragma unroll
            for (int i = 0; i < 2; ++i)
                #pragma unroll
                for (int j = 0; j < 4; ++j)
                    acc[i][j] = fmaf(wa[i], ba[j], acc[i][j]);
        }
        __syncthreads();
    }
    #pragma unroll
    for (int i = 0; i < 2; ++i) {
        float bias = bfu[o0 + i];
        float4 o4;
        o4.x = gelu_fast(acc[i][0] + bias);
        o4.y = gelu_fast(acc[i][1] + bias);
        o4.z = gelu_fast(acc[i][2] + bias);
        o4.w = gelu_fast(acc[i][3] + bias);
        *reinterpret_cast<float4*>(
            &out[(b * 64 + (o0 + i)) * 512 + tt0 + t0]) = o4;
    }
}

extern "C" void kernel_launch(void* const* d_in, const int* in_sizes, int n_in,
                              void* d_out, int out_size, void* d_ws, size_t ws_size,
                              hipStream_t stream) {
    const float* feat = (const float*)d_in[0];
    const float* w0  = (const float*)d_in[1];
    const float* b0  = (const float*)d_in[2];
    const float* w1  = (const float*)d_in[3];
    const float* b1  = (const float*)d_in[4];
    const float* w2  = (const float*)d_in[5];
    const float* b2  = (const float*)d_in[6];
    const float* wpj = (const float*)d_in[7];
    const float* bpj = (const float*)d_in[8];
    const float* wr  = (const float*)d_in[9];
    const float* br  = (const float*)d_in[10];
    const float* wf  = (const float*)d_in[11];
    const float* bfu = (const float*)d_in[12];

    float* ws = (float*)d_ws;
    float* avgb = ws;
    float* maxb = ws + (size_t)NROWS * T_;
    float* seqb = ws + 2 * (size_t)NROWS * T_;

    mono_kernel<<<NROWS, 128, 0, stream>>>(feat, w0, b0, w1, b1, w2, b2,
                                           wpj, bpj, wr, br, avgb, maxb, seqb);
    fuse_kernel<<<dim3(16, 32), 256, 0, stream>>>(avgb, maxb, seqb, wf, bfu,
                                                  (float*)d_out);
}

// Round 10
// 42.519 us; speedup vs baseline: 14.4099x; 14.4099x over previous
//
#include <hip/hip_runtime.h>
#include <math.h>

#define B_    32
#define C_    64
#define T_    512
#define NROWS (B_ * C_)
#define CMAX_ 16
#define FEPS  1.1920929e-07f

// gelu via sigmoid form of the tanh approximation (max abs err ~3e-4)
__device__ __forceinline__ float gelu_fast(float x) {
    float y = fmaf(0.044715f * x * x, x, x);
    float e = __builtin_exp2f(-2.3022808f * y);
    return x * __builtin_amdgcn_rcpf(1.0f + e);
}

// ---------------- mono kernel: rFFT + top-3 + fold/conv/pools/seq ----------
// One row per block, 128 threads (2 waves).
__global__ __launch_bounds__(128) void mono_kernel(
    const float* __restrict__ feat,
    const float* __restrict__ w0, const float* __restrict__ b0,
    const float* __restrict__ w1, const float* __restrict__ b1,
    const float* __restrict__ w2, const float* __restrict__ b2,
    const float* __restrict__ wpj, const float* __restrict__ bpj,
    const float* __restrict__ wr, const float* __restrict__ br,
    float* __restrict__ avg_out, float* __restrict__ max_out,
    float* __restrict__ seq_out)
{
    __shared__ float rowp[1040];         // rowp[2+i] = row[i]; tail zero-filled
    __shared__ __align__(16) float2 FA[256];
    __shared__ __align__(16) float2 FB[256];
    __shared__ float WeffS[80];
    __shared__ float wtopS[6];
    __shared__ int   itopS[6];
    __shared__ int   ipS[9];             // P[3], cyc[3], base[3]
    __shared__ float bwS[3];

    const int tid = threadIdx.x;         // 0..127
    const int r = blockIdx.x;

    // ---- stage row into padded LDS; zero tail so no clamps needed ----
    {
        float4 v = reinterpret_cast<const float4*>(feat + (size_t)r * T_)[tid];
        int bi = 2 + tid * 4;
        rowp[bi + 0] = v.x; rowp[bi + 1] = v.y;
        rowp[bi + 2] = v.z; rowp[bi + 3] = v.w;
    }
    for (int i = 514 + tid; i < 1040; i += 128) rowp[i] = 0.f;
    if (tid == 0) { rowp[0] = 0.f; rowp[1] = 0.f; }
    if (tid < 80) {
        int i = tid;
        if (i < 75) {
            int k = i / 25, ij = i % 25, ii = ij / 5, jj = ij % 5;
            float w = wpj[2] * w2[k * 25 + ii * 5 + jj];
            if (ii >= 1 && ii <= 3 && jj >= 1 && jj <= 3)
                w += wpj[1] * w1[k * 9 + (ii - 1) * 3 + (jj - 1)];
            if (ii == 2 && jj == 2) w += wpj[0] * w0[k];
            WeffS[i] = w;
        } else if (i == 75) {
            WeffS[75] = wpj[0] * b0[0] + wpj[1] * b1[0] + wpj[2] * b2[0] + bpj[0];
        } else if (i <= 78) {
            WeffS[i] = wr[i - 76];
        } else {
            WeffS[79] = br[0];
        }
    }
    __syncthreads();

    // ---- pack reals into 256 complex: z[n] = x[2n] + i x[2n+1] ----
    FA[tid]       = make_float2(rowp[2 + 2 * tid],         rowp[2 + 2 * tid + 1]);
    FA[tid + 128] = make_float2(rowp[2 + 2 * (tid + 128)], rowp[2 + 2 * (tid + 128) + 1]);
    __syncthreads();

    // ---- 8-stage Stockham radix-2 FFT (256-pt complex), ping-pong FA/FB ----
    {
        float2* src = FA;
        float2* dst = FB;
        #pragma unroll
        for (int s = 1; s <= 8; ++s) {
            const int l = 1 << (s - 1);
            const int p = tid & (l - 1);
            const int i0 = 2 * tid - p;
            const float rev = (float)p * (0.5f / (float)l);   // e^{-i pi p/l}
            const float cw =  __builtin_amdgcn_cosf(rev);
            const float sw = -__builtin_amdgcn_sinf(rev);
            float2 a = src[tid];
            float2 b = src[tid + 128];
            float tr = cw * b.x - sw * b.y;
            float ti = cw * b.y + sw * b.x;
            dst[i0]     = make_float2(a.x + tr, a.y + ti);
            dst[i0 + l] = make_float2(a.x - tr, a.y - ti);
            __syncthreads();
            float2* tmp = src; src = dst; dst = tmp;
        }
    }

    // ---- rfft unpack: thread j -> bins k = j+1 and k = j+129 ----
    float v[2]; int id[2];
    #pragma unroll
    for (int q = 0; q < 2; ++q) {
        const int k = 1 + tid + 128 * q;
        float2 A  = FA[k & 255];
        float2 Bv = FA[(256 - k) & 255];
        float Er = 0.5f * (A.x + Bv.x);
        float Ei = 0.5f * (A.y - Bv.y);
        float Or = 0.5f * (A.y + Bv.y);
        float Oi = 0.5f * (Bv.x - A.x);
        const float rev = (float)k * (1.0f / 512.0f);
        float sth = __builtin_amdgcn_sinf(rev);
        float cth = __builtin_amdgcn_cosf(rev);
        float Fr = Er + cth * Or + sth * Oi;
        float Fi = Ei + cth * Oi - sth * Or;
        v[q] = sqrtf(Fr * Fr + Fi * Fi);
        id[q] = k;
    }

    // ---- wave-local top-3 then cross-wave merge ----
    {
        const int wv = tid >> 6;
        float vals[3]; int idxs[3];
        #pragma unroll
        for (int kk = 0; kk < 3; ++kk) {
            float bv = v[0]; int bi = id[0];
            if (v[1] > bv || (v[1] == bv && id[1] < bi)) { bv = v[1]; bi = id[1]; }
            #pragma unroll
            for (int off = 32; off >= 1; off >>= 1) {
                float ov = __shfl_xor(bv, off, 64);
                int   oi = __shfl_xor(bi, off, 64);
                if (ov > bv || (ov == bv && oi < bi)) { bv = ov; bi = oi; }
            }
            vals[kk] = bv; idxs[kk] = bi;
            #pragma unroll
            for (int q = 0; q < 2; ++q)
                if (id[q] == bi) v[q] = -1e30f;
        }
        if ((tid & 63) == 0) {
            #pragma unroll
            for (int kk = 0; kk < 3; ++kk) {
                wtopS[wv * 3 + kk] = vals[kk];
                itopS[wv * 3 + kk] = idxs[kk];
            }
        }
    }
    __syncthreads();
    if (tid == 0) {
        float vv[6]; int ii[6];
        #pragma unroll
        for (int q = 0; q < 6; ++q) { vv[q] = wtopS[q]; ii[q] = itopS[q]; }
        float vals[3]; int idxs[3];
        #pragma unroll
        for (int kk = 0; kk < 3; ++kk) {
            float bv = vv[0]; int bi = ii[0];
            #pragma unroll
            for (int q = 1; q < 6; ++q)
                if (vv[q] > bv || (vv[q] == bv && ii[q] < bi)) { bv = vv[q]; bi = ii[q]; }
            vals[kk] = bv; idxs[kk] = bi;
            #pragma unroll
            for (int q = 0; q < 6; ++q)
                if (ii[q] == bi) vv[q] = -1e30f;
        }
        float m = fmaxf(vals[0], fmaxf(vals[1], vals[2]));
        float e0 = expf(vals[0] - m), e1 = expf(vals[1] - m), e2 = expf(vals[2] - m);
        float inv = 1.0f / (e0 + e1 + e2);
        bwS[0] = e0 * inv; bwS[1] = e1 * inv; bwS[2] = e2 * inv;
        #pragma unroll
        for (int kk = 0; kk < 3; ++kk) {
            int fi = idxs[kk];
            int P = T_ / fi;
            P = P < 32 ? 32 : (P > 512 ? 512 : P);
            int cyc = T_ / P;
            ipS[kk] = P; ipS[3 + kk] = cyc; ipS[6 + kk] = T_ - cyc * P;
        }
    }
    __syncthreads();

    // ---- fold + conv + pools + merged seq ----
    const int P0  = __builtin_amdgcn_readfirstlane(ipS[0]);
    const int P1  = __builtin_amdgcn_readfirstlane(ipS[1]);
    const int P2  = __builtin_amdgcn_readfirstlane(ipS[2]);
    const int cy0 = __builtin_amdgcn_readfirstlane(ipS[3]);
    const int cy1 = __builtin_amdgcn_readfirstlane(ipS[4]);
    const int cy2 = __builtin_amdgcn_readfirstlane(ipS[5]);
    const int bs0 = __builtin_amdgcn_readfirstlane(ipS[6]);
    const int bs1 = __builtin_amdgcn_readfirstlane(ipS[7]);
    const int bs2 = __builtin_amdgcn_readfirstlane(ipS[8]);
    const float bw0 = bwS[0], bw1 = bwS[1], bw2 = bwS[2];
    const float beff = WeffS[75], wr0 = WeffS[76], wr1 = WeffS[77],
                wr2 = WeffS[78], bres = WeffS[79];

    int maxP = P0 > P1 ? P0 : P1; maxP = maxP > P2 ? maxP : P2;
    const int PkA[3]  = {P0, P1, P2};
    const int cykA[3] = {cy0, cy1, cy2};
    const int bskA[3] = {bs0, bs1, bs2};
    const int woff = tid & 64;          // wave base within chunk

    #pragma unroll 1
    for (int pc = 0; pc < T_; pc += 128) {
        const int p = pc + tid;
        const int wb = __builtin_amdgcn_readfirstlane(pc + woff);
        if (wb >= maxP) {
            avg_out[r * T_ + p] = 0.f;
            max_out[r * T_ + p] = 0.f;
            seq_out[r * T_ + p] = 0.f;
            continue;
        }
        int c0 = (P0 > wb) ? cy0 : 0;
        int c1 = (P1 > wb) ? cy1 : 0;
        int c2 = (P2 > wb) ? cy2 : 0;
        int cymax = c0 > c1 ? c0 : c1; cymax = cymax > c2 ? cymax : c2;
        cymax = __builtin_amdgcn_readfirstlane(cymax);

        float zacc[CMAX_];
        #pragma unroll
        for (int i = 0; i < CMAX_; ++i) zacc[i] = beff;

        // ---- conv: software-pipelined taps; one k live at a time (no spill) ----
        #pragma unroll 1
        for (int k = 0; k < 3; ++k) {
            const int P = PkA[k];
            if (wb >= P) continue;          // wave-uniform skip
            const int cy = cykA[k];
            const int bs = bskA[k];
            float Wk[5][5];
            #pragma unroll
            for (int i = 0; i < 5; ++i)
                #pragma unroll
                for (int j = 0; j < 5; ++j)
                    Wk[i][j] = WeffS[k * 25 + i * 5 + j];
            bool mdw[5];
            #pragma unroll
            for (int dw = -2; dw <= 2; ++dw)
                mdw[dw + 2] = ((unsigned)(p + dw) < (unsigned)P);
            const int base = bs + p;        // rowp index of dw=-2 tap (pad +2 cancels)
            float cur[5], nxt[5];
            #pragma unroll
            for (int dw = 0; dw < 5; ++dw) { cur[dw] = rowp[base + dw]; nxt[dw] = 0.f; }
            #pragma unroll
            for (int hh = 0; hh < CMAX_; ++hh) {
                if (hh < cy) {              // lane-uniform guard
                    if (hh + 1 < cy) {      // prefetch next window under FMAs
                        const int a = base + (hh + 1) * P;
                        #pragma unroll
                        for (int dw = 0; dw < 5; ++dw) nxt[dw] = rowp[a + dw];
                    }
                    float w[5];
                    #pragma unroll
                    for (int dw = 0; dw < 5; ++dw) w[dw] = mdw[dw] ? cur[dw] : 0.f;
                    #pragma unroll
                    for (int dh = -2; dh <= 2; ++dh) {
                        const int cc = hh - dh;     // compile-time
                        if (cc >= 0 && cc < CMAX_) {
                            #pragma unroll
                            for (int dw = 0; dw < 5; ++dw)
                                zacc[cc] = fmaf(Wk[dh + 2][dw], w[dw], zacc[cc]);
                        }
                    }
                    #pragma unroll
                    for (int dw = 0; dw < 5; ++dw) cur[dw] = nxt[dw];
                }
            }
        }

        // ---- pools + merged branch sums ----
        float avg_num = 0.f, den = 0.f, mx = -3.402823466e38f;
        float s0 = 0.f, s1 = 0.f, s2 = 0.f;
        int anyv = 0;
        const int pl0 = (p < P0), pl1 = (p < P1), pl2 = (p < P2);
        #pragma unroll
        for (int cc = 0; cc < CMAX_; ++cc) {
            if (cc < cymax) {               // uniform guard
                int m0 = (cc < cy0) & pl0;
                int m1 = (cc < cy1) & pl1;
                int m2 = (cc < cy2) & pl2;
                float x0v = m0 ? rowp[2 + bs0 + cc * P0 + p] : 0.f;
                float x1v = m1 ? rowp[2 + bs1 + cc * P1 + p] : 0.f;
                float x2v = m2 ? rowp[2 + bs2 + cc * P2 + p] : 0.f;
                float res = fmaf(wr0, x0v, fmaf(wr1, x1v, fmaf(wr2, x2v, bres)));
                float z = gelu_fast(zacc[cc]) + res;
                s0 += x0v; s1 += x1v; s2 += x2v;
                int mm = m0 | m1 | m2;
                float cm = mm ? 1.f : 0.f;
                avg_num += z * cm;
                den += cm;
                mx = mm ? fmaxf(mx, z) : mx;
                anyv |= mm;
            }
        }
        float avg = avg_num / (den + FEPS);
        float mpool = anyv ? mx : 0.f;

        float seq = 0.f;
        seq = fmaf(bw0, pl0 ? s0 / ((float)cy0 + FEPS) : 0.f, seq);
        seq = fmaf(bw1, pl1 ? s1 / ((float)cy1 + FEPS) : 0.f, seq);
        seq = fmaf(bw2, pl2 ? s2 / ((float)cy2 + FEPS) : 0.f, seq);

        avg_out[r * T_ + p] = avg;
        max_out[r * T_ + p] = mpool;
        seq_out[r * T_ + p] = seq;
    }
}

// ---------- fuse GEMM + gelu ----------
// grid (16 t-tiles, 32 b), 256 threads, 64o x 32t tile, 2o x 4t micro.
__global__ __launch_bounds__(256) void fuse_kernel(
    const float* __restrict__ avgb, const float* __restrict__ maxb,
    const float* __restrict__ seqb,
    const float* __restrict__ wf, const float* __restrict__ bfu,
    float* __restrict__ out)
{
    __shared__ float wT[64][70];    // wT[c][o]
    __shared__ float Bt[64][40];    // Bt[c][t]
    const int tid = threadIdx.x;
    const int b = blockIdx.y;
    const int tt0 = blockIdx.x * 32;
    const int og = tid >> 3;        // 0..31
    const int tg = tid & 7;         // 0..7
    const int o0 = og * 2;
    const int t0 = tg * 4;

    float acc[2][4];
    #pragma unroll
    for (int i = 0; i < 2; ++i)
        #pragma unroll
        for (int j = 0; j < 4; ++j) acc[i][j] = 0.f;

    const float* srcs[3] = {avgb, maxb, seqb};
    for (int g = 0; g < 3; ++g) {
        const float* __restrict__ src = srcs[g];
        #pragma unroll
        for (int it = 0; it < 2; ++it) {
            int idx = tid + it * 256;          // 0..511
            int c = idx >> 3, t4 = idx & 7;
            float4 vv = reinterpret_cast<const float4*>(
                            &src[(b * 64 + c) * 512 + tt0])[t4];
            *reinterpret_cast<float4*>(&Bt[c][t4 * 4]) = vv;
        }
        #pragma unroll
        for (int it = 0; it < 16; ++it) {
            int i = tid + it * 256;            // 0..4095
            int c = i & 63, o = i >> 6;
            wT[c][o] = wf[o * 192 + g * 64 + c];
        }
        __syncthreads();
        for (int c = 0; c < 64; ++c) {
            float2 wv = *reinterpret_cast<const float2*>(&wT[c][o0]);
            float4 bv = *reinterpret_cast<const float4*>(&Bt[c][t0]);
            const float wa[2] = {wv.x, wv.y};
            const float ba[4] = {bv.x, bv.y, bv.z, bv.w};
            #pragma unroll
            for (int i = 0; i < 2; ++i)
                #pragma unroll
                for (int j = 0; j < 4; ++j)
                    acc[i][j] = fmaf(wa[i], ba[j], acc[i][j]);
        }
        __syncthreads();
    }
    #pragma unroll
    for (int i = 0; i < 2; ++i) {
        float bias = bfu[o0 + i];
        float4 o4;
        o4.x = gelu_fast(acc[i][0] + bias);
        o4.y = gelu_fast(acc[i][1] + bias);
        o4.z = gelu_fast(acc[i][2] + bias);
        o4.w = gelu_fast(acc[i][3] + bias);
        *reinterpret_cast<float4*>(
            &out[(b * 64 + (o0 + i)) * 512 + tt0 + t0]) = o4;
    }
}

extern "C" void kernel_launch(void* const* d_in, const int* in_sizes, int n_in,
                              void* d_out, int out_size, void* d_ws, size_t ws_size,
                              hipStream_t stream) {
    const float* feat = (const float*)d_in[0];
    const float* w0  = (const float*)d_in[1];
    const float* b0  = (const float*)d_in[2];
    const float* w1  = (const float*)d_in[3];
    const float* b1  = (const float*)d_in[4];
    const float* w2  = (const float*)d_in[5];
    const float* b2  = (const float*)d_in[6];
    const float* wpj = (const float*)d_in[7];
    const float* bpj = (const float*)d_in[8];
    const float* wr  = (const float*)d_in[9];
    const float* br  = (const float*)d_in[10];
    const float* wf  = (const float*)d_in[11];
    const float* bfu = (const float*)d_in[12];

    float* ws = (float*)d_ws;
    float* avgb = ws;
    float* maxb = ws + (size_t)NROWS * T_;
    float* seqb = ws + 2 * (size_t)NROWS * T_;

    mono_kernel<<<NROWS, 128, 0, stream>>>(feat, w0, b0, w1, b1, w2, b2,
                                           wpj, bpj, wr, br, avgb, maxb, seqb);
    fuse_kernel<<<dim3(16, 32), 256, 0, stream>>>(avgb, maxb, seqb, wf, bfu,
                                                  (float*)d_out);
}

// Round 11
// 41.108 us; speedup vs baseline: 14.9045x; 1.0343x over previous
//
#include <hip/hip_runtime.h>
#include <math.h>

#define B_    32
#define C_    64
#define T_    512
#define NROWS (B_ * C_)
#define CMAX_ 16
#define FEPS  1.1920929e-07f

// gelu via sigmoid form of the tanh approximation (max abs err ~3e-4)
__device__ __forceinline__ float gelu_fast(float x) {
    float y = fmaf(0.044715f * x * x, x, x);
    float e = __builtin_exp2f(-2.3022808f * y);
    return x * __builtin_amdgcn_rcpf(1.0f + e);
}

// ---------------- mono kernel: rFFT + top-3 + fold/conv/pools/seq ----------
// One row per block, 128 threads (2 waves).
// FFT: two independent wave-local 128-pt complex FFTs (even/odd), no barriers
// inside stages (same-wave DS ordering), then one combine+unpack step.
__global__ __launch_bounds__(128) void mono_kernel(
    const float* __restrict__ feat,
    const float* __restrict__ w0, const float* __restrict__ b0,
    const float* __restrict__ w1, const float* __restrict__ b1,
    const float* __restrict__ w2, const float* __restrict__ b2,
    const float* __restrict__ wpj, const float* __restrict__ bpj,
    const float* __restrict__ wr, const float* __restrict__ br,
    float* __restrict__ avg_out, float* __restrict__ max_out,
    float* __restrict__ seq_out)
{
    __shared__ float rowp[1040];         // rowp[2+i] = row[i]; tail zero-filled
    __shared__ __align__(16) float2 FA[256];   // [0:128) wave0, [128:256) wave1
    __shared__ __align__(16) float2 FB[256];
    __shared__ float WeffS[80];
    __shared__ float wtopS[6];
    __shared__ int   itopS[6];
    __shared__ int   ipS[9];             // P[3], cyc[3], base[3]
    __shared__ float bwS[3];

    const int tid = threadIdx.x;         // 0..127
    const int lane = tid & 63;
    const int wv = tid >> 6;
    const int r = blockIdx.x;

    // ---- stage row into padded LDS; zero tail so no clamps needed ----
    {
        float4 v = reinterpret_cast<const float4*>(feat + (size_t)r * T_)[tid];
        int bi = 2 + tid * 4;
        rowp[bi + 0] = v.x; rowp[bi + 1] = v.y;
        rowp[bi + 2] = v.z; rowp[bi + 3] = v.w;
    }
    for (int i = 514 + tid; i < 1040; i += 128) rowp[i] = 0.f;
    if (tid == 0) { rowp[0] = 0.f; rowp[1] = 0.f; }
    if (tid < 80) {
        int i = tid;
        if (i < 75) {
            int k = i / 25, ij = i % 25, ii = ij / 5, jj = ij % 5;
            float w = wpj[2] * w2[k * 25 + ii * 5 + jj];
            if (ii >= 1 && ii <= 3 && jj >= 1 && jj <= 3)
                w += wpj[1] * w1[k * 9 + (ii - 1) * 3 + (jj - 1)];
            if (ii == 2 && jj == 2) w += wpj[0] * w0[k];
            WeffS[i] = w;
        } else if (i == 75) {
            WeffS[75] = wpj[0] * b0[0] + wpj[1] * b1[0] + wpj[2] * b2[0] + bpj[0];
        } else if (i <= 78) {
            WeffS[i] = wr[i - 76];
        } else {
            WeffS[79] = br[0];
        }
    }
    __syncthreads();

    // ---- pack: wave wv owns z_wv[n] = x[4n+2wv] + i x[4n+1+2wv], n=0..127 ----
    {
        float2* Fw = FA + (wv << 7);
        #pragma unroll
        for (int n = lane; n < 128; n += 64)
            Fw[n] = make_float2(rowp[2 + 4 * n + 2 * wv], rowp[3 + 4 * n + 2 * wv]);
    }

    // ---- 7-stage wave-local Stockham 128-pt FFT (no barriers) ----
    {
        float2* src = FA + (wv << 7);
        float2* dst = FB + (wv << 7);
        #pragma unroll
        for (int s = 1; s <= 7; ++s) {
            const int l = 1 << (s - 1);
            const int pl = lane & (l - 1);
            const int i0 = 2 * lane - pl;
            const float rev = (float)pl * (0.5f / (float)l);   // e^{-i pi pl/l}
            const float cw =  __builtin_amdgcn_cosf(rev);
            const float sw = -__builtin_amdgcn_sinf(rev);
            float2 a = src[lane];
            float2 b = src[lane + 64];
            float tr = cw * b.x - sw * b.y;
            float ti = cw * b.y + sw * b.x;
            dst[i0]     = make_float2(a.x + tr, a.y + ti);
            dst[i0 + l] = make_float2(a.x - tr, a.y - ti);
            float2* tmp = src; src = dst; dst = tmp;
        }
        // 7 stages (odd) -> results in FB
    }
    __syncthreads();

    // ---- combine + rfft unpack ----
    // F256[k] = Fe[k&127] + w256^k * Fo[k&127]; thread j owns bins k1=j+1, k2=j+129.
    float v[2]; int id[2];
    {
        const float2* Fe = FB;
        const float2* Fo = FB + 128;
        const int k1 = tid + 1;
        const int a = k1 & 127;
        const int b = (128 - a) & 127;       // (-k1) mod 128
        float2 Fea = Fe[a], Foa = Fo[a], Feb = Fe[b], Fob = Fo[b];
        const float revw = (float)k1 * (1.0f / 256.0f);
        const float cw =  __builtin_amdgcn_cosf(revw);
        const float sw = -__builtin_amdgcn_sinf(revw);   // w = e^{-2pi i k1/256}
        // w*Foa, conj(w)*Fob
        float wfr = cw * Foa.x - sw * Foa.y, wfi = cw * Foa.y + sw * Foa.x;
        float cfr = cw * Fob.x + sw * Fob.y, cfi = cw * Fob.y - sw * Fob.x;
        // unpack twiddle for k1; k2 version is quarter-turn rotation
        const float revu = (float)k1 * (1.0f / 512.0f);
        const float su = __builtin_amdgcn_sinf(revu);
        const float cu = __builtin_amdgcn_cosf(revu);
        #pragma unroll
        for (int q = 0; q < 2; ++q) {
            const float sgn = q ? -1.f : 1.f;
            // A = F256[k], Bv = F256[(256-k)&255]
            float Ax = Fea.x + sgn * wfr, Ay = Fea.y + sgn * wfi;
            float Bx = Feb.x + sgn * cfr, By = Feb.y + sgn * cfi;
            float Er = 0.5f * (Ax + Bx);
            float Ei = 0.5f * (Ay - By);
            float Or = 0.5f * (Ay + By);
            float Oi = 0.5f * (Bx - Ax);
            float cth = q ? -su : cu;     // cos(revu + q*0.25 rev)
            float sth = q ?  cu : su;     // sin(revu + q*0.25 rev)
            float Fr = Er + cth * Or + sth * Oi;
            float Fi = Ei + cth * Oi - sth * Or;
            v[q] = sqrtf(Fr * Fr + Fi * Fi);
            id[q] = k1 + 128 * q;
        }
    }

    // ---- wave-local top-3 then cross-wave merge ----
    {
        float vals[3]; int idxs[3];
        #pragma unroll
        for (int kk = 0; kk < 3; ++kk) {
            float bv = v[0]; int bi = id[0];
            if (v[1] > bv || (v[1] == bv && id[1] < bi)) { bv = v[1]; bi = id[1]; }
            #pragma unroll
            for (int off = 32; off >= 1; off >>= 1) {
                float ov = __shfl_xor(bv, off, 64);
                int   oi = __shfl_xor(bi, off, 64);
                if (ov > bv || (ov == bv && oi < bi)) { bv = ov; bi = oi; }
            }
            vals[kk] = bv; idxs[kk] = bi;
            #pragma unroll
            for (int q = 0; q < 2; ++q)
                if (id[q] == bi) v[q] = -1e30f;
        }
        if (lane == 0) {
            #pragma unroll
            for (int kk = 0; kk < 3; ++kk) {
                wtopS[wv * 3 + kk] = vals[kk];
                itopS[wv * 3 + kk] = idxs[kk];
            }
        }
    }
    __syncthreads();
    if (tid == 0) {
        float vv[6]; int ii[6];
        #pragma unroll
        for (int q = 0; q < 6; ++q) { vv[q] = wtopS[q]; ii[q] = itopS[q]; }
        float vals[3]; int idxs[3];
        #pragma unroll
        for (int kk = 0; kk < 3; ++kk) {
            float bv = vv[0]; int bi = ii[0];
            #pragma unroll
            for (int q = 1; q < 6; ++q)
                if (vv[q] > bv || (vv[q] == bv && ii[q] < bi)) { bv = vv[q]; bi = ii[q]; }
            vals[kk] = bv; idxs[kk] = bi;
            #pragma unroll
            for (int q = 0; q < 6; ++q)
                if (ii[q] == bi) vv[q] = -1e30f;
        }
        float m = fmaxf(vals[0], fmaxf(vals[1], vals[2]));
        float e0 = expf(vals[0] - m), e1 = expf(vals[1] - m), e2 = expf(vals[2] - m);
        float inv = 1.0f / (e0 + e1 + e2);
        bwS[0] = e0 * inv; bwS[1] = e1 * inv; bwS[2] = e2 * inv;
        #pragma unroll
        for (int kk = 0; kk < 3; ++kk) {
            int fi = idxs[kk];
            int P = T_ / fi;
            P = P < 32 ? 32 : (P > 512 ? 512 : P);
            int cyc = T_ / P;
            ipS[kk] = P; ipS[3 + kk] = cyc; ipS[6 + kk] = T_ - cyc * P;
        }
    }
    __syncthreads();

    // ---- fold + conv + pools + merged seq ----
    const int P0  = __builtin_amdgcn_readfirstlane(ipS[0]);
    const int P1  = __builtin_amdgcn_readfirstlane(ipS[1]);
    const int P2  = __builtin_amdgcn_readfirstlane(ipS[2]);
    const int cy0 = __builtin_amdgcn_readfirstlane(ipS[3]);
    const int cy1 = __builtin_amdgcn_readfirstlane(ipS[4]);
    const int cy2 = __builtin_amdgcn_readfirstlane(ipS[5]);
    const int bs0 = __builtin_amdgcn_readfirstlane(ipS[6]);
    const int bs1 = __builtin_amdgcn_readfirstlane(ipS[7]);
    const int bs2 = __builtin_amdgcn_readfirstlane(ipS[8]);
    const float bw0 = bwS[0], bw1 = bwS[1], bw2 = bwS[2];
    const float beff = WeffS[75], wr0 = WeffS[76], wr1 = WeffS[77],
                wr2 = WeffS[78], bres = WeffS[79];

    int maxP = P0 > P1 ? P0 : P1; maxP = maxP > P2 ? maxP : P2;
    const int PkA[3]  = {P0, P1, P2};
    const int cykA[3] = {cy0, cy1, cy2};
    const int bskA[3] = {bs0, bs1, bs2};
    const int woff = tid & 64;          // wave base within chunk

    #pragma unroll 1
    for (int pc = 0; pc < T_; pc += 128) {
        const int p = pc + tid;
        const int wb = __builtin_amdgcn_readfirstlane(pc + woff);
        if (wb >= maxP) {
            avg_out[r * T_ + p] = 0.f;
            max_out[r * T_ + p] = 0.f;
            seq_out[r * T_ + p] = 0.f;
            continue;
        }
        int c0 = (P0 > wb) ? cy0 : 0;
        int c1 = (P1 > wb) ? cy1 : 0;
        int c2 = (P2 > wb) ? cy2 : 0;
        int cymax = c0 > c1 ? c0 : c1; cymax = cymax > c2 ? cymax : c2;
        cymax = __builtin_amdgcn_readfirstlane(cymax);

        float zacc[CMAX_];
        #pragma unroll
        for (int i = 0; i < CMAX_; ++i) zacc[i] = beff;

        // ---- conv: branch-free groups of 4 rows; invalid rows read zero-tail ----
        #pragma unroll 1
        for (int k = 0; k < 3; ++k) {
            const int P = PkA[k];
            if (wb >= P) continue;          // wave-uniform skip
            const int cy = cykA[k];
            const int bs = bskA[k];
            float Wk[5][5];
            #pragma unroll
            for (int i = 0; i < 5; ++i)
                #pragma unroll
                for (int j = 0; j < 5; ++j)
                    Wk[i][j] = WeffS[k * 25 + i * 5 + j];
            bool mdw[5];
            #pragma unroll
            for (int dw = -2; dw <= 2; ++dw)
                mdw[dw + 2] = ((unsigned)(p + dw) < (unsigned)P);
            const int base = bs + p;        // rowp idx of dw=-2 tap (+2 pad cancels)
            #pragma unroll
            for (int g = 0; g < 4; ++g) {
                if (4 * g < cy) {           // uniform group guard
                    #pragma unroll
                    for (int h4 = 0; h4 < 4; ++h4) {
                        const int hh = 4 * g + h4;
                        const int hoff = (hh < cy) ? 0 : 4096;     // uniform
                        int a0 = base + hh * P + hoff;
                        a0 = a0 > 1031 ? 1031 : a0;                // tail reads 0
                        float w[5];
                        #pragma unroll
                        for (int dw = 0; dw < 5; ++dw)
                            w[dw] = mdw[dw] ? rowp[a0 + dw] : 0.f;
                        #pragma unroll
                        for (int dh = -2; dh <= 2; ++dh) {
                            const int cc = hh - dh;     // compile-time
                            if (cc >= 0 && cc < CMAX_) {
                                #pragma unroll
                                for (int dw = 0; dw < 5; ++dw)
                                    zacc[cc] = fmaf(Wk[dh + 2][dw], w[dw], zacc[cc]);
                            }
                        }
                    }
                }
            }
        }

        // ---- pools + merged branch sums: branch-free groups of 4 ----
        float avg_num = 0.f, den = 0.f, mx = -3.402823466e38f;
        float s0 = 0.f, s1 = 0.f, s2 = 0.f;
        int anyv = 0;
        const int pl0 = (p < P0), pl1 = (p < P1), pl2 = (p < P2);
        #pragma unroll
        for (int cg = 0; cg < 4; ++cg) {
            if (4 * cg < cymax) {           // uniform group guard
                #pragma unroll
                for (int c4 = 0; c4 < 4; ++c4) {
                    const int cc = 4 * cg + c4;
                    int m0 = (cc < cy0) & pl0;
                    int m1 = (cc < cy1) & pl1;
                    int m2 = (cc < cy2) & pl2;
                    int a0 = 2 + bs0 + cc * P0 + p; a0 = a0 > 1036 ? 1036 : a0;
                    int a1 = 2 + bs1 + cc * P1 + p; a1 = a1 > 1036 ? 1036 : a1;
                    int a2 = 2 + bs2 + cc * P2 + p; a2 = a2 > 1036 ? 1036 : a2;
                    float x0v = m0 ? rowp[a0] : 0.f;
                    float x1v = m1 ? rowp[a1] : 0.f;
                    float x2v = m2 ? rowp[a2] : 0.f;
                    float res = fmaf(wr0, x0v, fmaf(wr1, x1v, fmaf(wr2, x2v, bres)));
                    float z = gelu_fast(zacc[cc]) + res;
                    s0 += x0v; s1 += x1v; s2 += x2v;
                    int mm = m0 | m1 | m2;
                    float cm = mm ? 1.f : 0.f;
                    avg_num += z * cm;
                    den += cm;
                    mx = mm ? fmaxf(mx, z) : mx;
                    anyv |= mm;
                }
            }
        }
        float avg = avg_num / (den + FEPS);
        float mpool = anyv ? mx : 0.f;

        float seq = 0.f;
        seq = fmaf(bw0, pl0 ? s0 / ((float)cy0 + FEPS) : 0.f, seq);
        seq = fmaf(bw1, pl1 ? s1 / ((float)cy1 + FEPS) : 0.f, seq);
        seq = fmaf(bw2, pl2 ? s2 / ((float)cy2 + FEPS) : 0.f, seq);

        avg_out[r * T_ + p] = avg;
        max_out[r * T_ + p] = mpool;
        seq_out[r * T_ + p] = seq;
    }
}

// ---------- fuse GEMM + gelu ----------
// grid (16 t-tiles, 32 b), 256 threads, 64o x 32t tile, 2o x 4t micro.
__global__ __launch_bounds__(256) void fuse_kernel(
    const float* __restrict__ avgb, const float* __restrict__ maxb,
    const float* __restrict__ seqb,
    const float* __restrict__ wf, const float* __restrict__ bfu,
    float* __restrict__ out)
{
    __shared__ float wT[64][70];    // wT[c][o]
    __shared__ float Bt[64][40];    // Bt[c][t]
    const int tid = threadIdx.x;
    const int b = blockIdx.y;
    const int tt0 = blockIdx.x * 32;
    const int og = tid >> 3;        // 0..31
    const int tg = tid & 7;         // 0..7
    const int o0 = og * 2;
    const int t0 = tg * 4;

    float acc[2][4];
    #pragma unroll
    for (int i = 0; i < 2; ++i)
        #pragma unroll
        for (int j = 0; j < 4; ++j) acc[i][j] = 0.f;

    const float* srcs[3] = {avgb, maxb, seqb};
    for (int g = 0; g < 3; ++g) {
        const float* __restrict__ src = srcs[g];
        #pragma unroll
        for (int it = 0; it < 2; ++it) {
            int idx = tid + it * 256;          // 0..511
            int c = idx >> 3, t4 = idx & 7;
            float4 vv = reinterpret_cast<const float4*>(
                            &src[(b * 64 + c) * 512 + tt0])[t4];
            *reinterpret_cast<float4*>(&Bt[c][t4 * 4]) = vv;
        }
        #pragma unroll
        for (int it = 0; it < 16; ++it) {
            int i = tid + it * 256;            // 0..4095
            int c = i & 63, o = i >> 6;
            wT[c][o] = wf[o * 192 + g * 64 + c];
        }
        __syncthreads();
        for (int c = 0; c < 64; ++c) {
            float2 wv = *reinterpret_cast<const float2*>(&wT[c][o0]);
            float4 bv = *reinterpret_cast<const float4*>(&Bt[c][t0]);
            const float wa[2] = {wv.x, wv.y};
            const float ba[4] = {bv.x, bv.y, bv.z, bv.w};
            #pragma unroll
            for (int i = 0; i < 2; ++i)
                #pragma unroll
                for (int j = 0; j < 4; ++j)
                    acc[i][j] = fmaf(wa[i], ba[j], acc[i][j]);
        }
        __syncthreads();
    }
    #pragma unroll
    for (int i = 0; i < 2; ++i) {
        float bias = bfu[o0 + i];
        float4 o4;
        o4.x = gelu_fast(acc[i][0] + bias);
        o4.y = gelu_fast(acc[i][1] + bias);
        o4.z = gelu_fast(acc[i][2] + bias);
        o4.w = gelu_fast(acc[i][3] + bias);
        *reinterpret_cast<float4*>(
            &out[(b * 64 + (o0 + i)) * 512 + tt0 + t0]) = o4;
    }
}

extern "C" void kernel_launch(void* const* d_in, const int* in_sizes, int n_in,
                              void* d_out, int out_size, void* d_ws, size_t ws_size,
                              hipStream_t stream) {
    const float* feat = (const float*)d_in[0];
    const float* w0  = (const float*)d_in[1];
    const float* b0  = (const float*)d_in[2];
    const float* w1  = (const float*)d_in[3];
    const float* b1  = (const float*)d_in[4];
    const float* w2  = (const float*)d_in[5];
    const float* b2  = (const float*)d_in[6];
    const float* wpj = (const float*)d_in[7];
    const float* bpj = (const float*)d_in[8];
    const float* wr  = (const float*)d_in[9];
    const float* br  = (const float*)d_in[10];
    const float* wf  = (const float*)d_in[11];
    const float* bfu = (const float*)d_in[12];

    float* ws = (float*)d_ws;
    float* avgb = ws;
    float* maxb = ws + (size_t)NROWS * T_;
    float* seqb = ws + 2 * (size_t)NROWS * T_;

    mono_kernel<<<NROWS, 128, 0, stream>>>(feat, w0, b0, w1, b1, w2, b2,
                                           wpj, bpj, wr, br, avgb, maxb, seqb);
    fuse_kernel<<<dim3(16, 32), 256, 0, stream>>>(avgb, maxb, seqb, wf, bfu,
                                                  (float*)d_out);
}